// Round 7
// baseline (8425.458 us; speedup 1.0000x reference)
//
#include <hip/hip_runtime.h>
#include <math.h>

#define HID 512
#define SEQ 512
#define EMB 345
#define NN  513
#define MPAD 576
#define H4  2048
#define H2  1024

// ---------------------------------------------------------------- GEMM (NT)
// C[m][n] = sum_k A[m][k]*B[n][k] (+ bias[n]); BM=BN=64, TK=16, 256 thr, 4x4
__global__ __launch_bounds__(256)
void gemm_nt(const float* __restrict__ A, int lda, long aStride,
             const float* __restrict__ B, int ldb, long bStride,
             const float* __restrict__ bias, long biasStride,
             float* __restrict__ C, int ldc, long cStride, int K)
{
    int z = blockIdx.z;
    A += (long)z * aStride; B += (long)z * bStride; C += (long)z * cStride;
    const float* bptr = bias ? bias + (long)z * biasStride : nullptr;
    __shared__ float As[16][68];
    __shared__ float Bs[16][68];
    int tid = threadIdx.x;
    int tx = tid & 15, ty = tid >> 4;
    int m0 = blockIdx.y * 64, n0 = blockIdx.x * 64;
    float acc[4][4] = {};
    for (int k0 = 0; k0 < K; k0 += 16) {
        #pragma unroll
        for (int i = 0; i < 4; i++) {
            int id = tid + 256 * i;
            int mn = id >> 4, kk = id & 15;
            int k = k0 + kk;
            As[kk][mn] = (k < K) ? A[(long)(m0 + mn) * lda + k] : 0.f;
            Bs[kk][mn] = (k < K) ? B[(long)(n0 + mn) * ldb + k] : 0.f;
        }
        __syncthreads();
        #pragma unroll
        for (int kk = 0; kk < 16; kk++) {
            float a[4], b[4];
            #pragma unroll
            for (int i = 0; i < 4; i++) a[i] = As[kk][ty * 4 + i];
            #pragma unroll
            for (int j = 0; j < 4; j++) b[j] = Bs[kk][tx * 4 + j];
            #pragma unroll
            for (int i = 0; i < 4; i++)
                #pragma unroll
                for (int j = 0; j < 4; j++) acc[i][j] += a[i] * b[j];
        }
        __syncthreads();
    }
    #pragma unroll
    for (int i = 0; i < 4; i++) {
        int m = m0 + ty * 4 + i;
        #pragma unroll
        for (int j = 0; j < 4; j++) {
            int n = n0 + tx * 4 + j;
            float v = acc[i][j];
            if (bptr) v += bptr[n];
            C[(long)m * ldc + n] = v;
        }
    }
}

// ---------------------------------------------------------------- LSTM layer
// fast activations: v_exp_f32 + v_rcp_f32 (~1e-6 rel err; tolerance is 0.39)
__device__ __forceinline__ float sigmf(float x)
{ return __builtin_amdgcn_rcpf(1.f + __expf(-x)); }
__device__ __forceinline__ float tanhf_fast(float x)
{ return 1.f - 2.f * __builtin_amdgcn_rcpf(1.f + __expf(2.f * x)); }
// x=+inf: exp=inf, rcp=0 -> 1; x=-inf: exp=0 -> -1. No NaN.

__device__ __forceinline__ bool badw(unsigned long long a)
{ return ((unsigned)a == 0xFFFFFFFFu) || ((unsigned)(a >> 32) == 0xFFFFFFFFu); }

// 256 WGs: wg>>7 = dir, (wg&127)*4 = cell base. WAVE = CELL: wave w owns
// cell cb+w entirely (lane = g*16 + kp; g gate, kp k-sixteenth of 32).
// Each thread holds 32 Whh weights in VGPRs (8 float4 — small enough that
// the allocator keeps them resident; R1/R5/R6 showed 128+ floats spill).
// Per step: cooperative poll of prev h (1 ull/thread, data-as-flag 0xFF
// sentinel) -> padded LDS (chunk stride 36 -> 2-way aliasing = free on
// b128) -> ONE barrier (double-buffered) -> 8 ds_read_b128 + 32 FMA ->
// 4 shfl_xor (k-reduce) + 3 shfl (gate gather) -> activation + 1-dword
// publish on lane 0. Everything after the barrier is intra-wave.
__global__ __launch_bounds__(256, 1)
void lstm_layer(const float* __restrict__ zin,   // [2][SEQ][H4]
                const float* __restrict__ Whh,   // [2][H4][HID]
                float* out)                      // [SEQ][H2], pre-memset 0xFF
{
    int wg  = blockIdx.x;
    int dir = wg >> 7;
    int cb  = (wg & 127) * 4;
    int tid = threadIdx.x;
    int w   = tid >> 6;          // wave = cell-in-group
    int l   = tid & 63;
    int g   = l >> 4;            // gate (torch order i,f,g,o)
    int kp  = l & 15;            // k-sixteenth (32 floats each)
    int cell = cb + w;
    long row = (long)g * 512 + cell;

    __shared__ float h_st[2][16 * 36];   // double-buffered h, padded chunks

    // register-resident weights: 32 floats/thread
    float4 wv[8];
    {
        const float4* wp = (const float4*)(Whh + ((long)dir * H4 + row) * HID + kp * 32);
        #pragma unroll
        for (int j = 0; j < 8; j++) wv[j] = wp[j];
    }

    const float* zin_d = zin + (long)dir * SEQ * H4;
    float c_st = 0.f;
    int hc = tid >> 4;           // staging chunk (element e=2*tid, chunk=e>>5)
    int ho = 2 * (tid & 15);     // offset within chunk

    for (int t = 0; t < SEQ; t++) {
        int at = (dir == 0) ? t : (SEQ - 1 - t);
        // zin prefetch (only kp==0 lanes need it), issued before the poll
        float zv = 0.f;
        if (kp == 0) zv = zin_d[(long)at * H4 + row];

        if (t == 0) {
            *(float2*)&h_st[0][hc * 36 + ho] = make_float2(0.f, 0.f);
        } else {
            int at_prev = (dir == 0) ? (t - 1) : (SEQ - t);
            const unsigned long long* src =
                (const unsigned long long*)(out + (long)at_prev * H2 + dir * HID) + tid;
            unsigned long long a = __hip_atomic_load(src, __ATOMIC_RELAXED, __HIP_MEMORY_SCOPE_AGENT);
            while (badw(a)) {
                __builtin_amdgcn_s_sleep(1);
                a = __hip_atomic_load(src, __ATOMIC_RELAXED, __HIP_MEMORY_SCOPE_AGENT);
            }
            union { unsigned long long u; float2 f; } cv; cv.u = a;
            *(float2*)&h_st[t & 1][hc * 36 + ho] = cv.f;
        }
        __syncthreads();       // the ONLY barrier per step (dbuf protects reuse)

        // MAC over own k-sixteenth (chunk kp, stride 36: 2-way aliasing, free)
        const float4* hp = (const float4*)&h_st[t & 1][kp * 36];
        float acc = 0.f;
        #pragma unroll
        for (int j = 0; j < 8; j++) {
            float4 h = hp[j];
            acc += wv[j].x * h.x + wv[j].y * h.y + wv[j].z * h.z + wv[j].w * h.w;
        }
        // k-reduce within the 16-lane gate group
        acc += __shfl_xor(acc, 1);
        acc += __shfl_xor(acc, 2);
        acc += __shfl_xor(acc, 4);
        acc += __shfl_xor(acc, 8);
        float zsum = acc + zv;             // full gate preact on kp==0 lanes
        // gate gather: lane 0 reads f/g/o preacts from lanes 16/32/48
        float zf = __shfl(zsum, 16);
        float zg = __shfl(zsum, 32);
        float zo = __shfl(zsum, 48);
        if (l == 0) {
            float cc = sigmf(zf) * c_st + sigmf(zsum) * tanhf_fast(zg);
            c_st = cc;
            float hh = sigmf(zo) * tanhf_fast(cc);
            // single publish: the out-write IS the ready flag
            __hip_atomic_store(out + (long)at * H2 + dir * HID + cell, hh,
                               __ATOMIC_RELAXED, __HIP_MEMORY_SCOPE_AGENT);
        }
    }
}

// ---------------------------------------------------------------- avail build
__global__ __launch_bounds__(256)
void build_avail(const float* __restrict__ lstm_out, float* __restrict__ avail)
{
    long idx = (long)blockIdx.x * 256 + threadIdx.x;   // over MPAD*H2
    if (idx >= (long)MPAD * H2) return;
    int i = (int)(idx >> 10);
    int c = (int)(idx & 1023);
    float v = 0.f;
    if (i >= 1 && i <= SEQ) v = lstm_out[(long)(i - 1) * H2 + c];
    avail[idx] = v;
}

// ---------------------------------------------------------------- transpose
__global__ __launch_bounds__(256)
void transpose_w(const float* __restrict__ W, float* __restrict__ WT, int rows, int cols)
{
    int idx = blockIdx.x * 256 + threadIdx.x;
    if (idx >= rows * cols) return;
    int rr = idx / cols, cc = idx % cols;
    WT[cc * rows + rr] = W[idx];
}

// ---------------------------------------------------------------- pair MLP
#define STR1 257
#define STR2 129
__global__ __launch_bounds__(256)
void pair_kernel(const float* __restrict__ Abuf, const float* __restrict__ Bbuf,
                 const float* __restrict__ b1, const float* __restrict__ W2T,
                 const float* __restrict__ b2, const float* __restrict__ W3T,
                 const float* __restrict__ b3, const float* __restrict__ W4,
                 const float* __restrict__ b4, float* __restrict__ S)
{
    __shared__ float At[8 * STR1];
    __shared__ float Bt[8 * STR1];
    __shared__ float b1s[256];
    __shared__ float h2s[64 * STR2];
    __shared__ float spart[4 * 64];
    int tid = threadIdx.x;
    int i0 = blockIdx.y * 8, j0 = blockIdx.x * 8;
    {
        int rr = tid >> 5;
        int cbase = (tid & 31) * 8;
        #pragma unroll
        for (int u = 0; u < 8; u++) {
            At[rr * STR1 + cbase + u] = Abuf[(long)(i0 + rr) * 256 + cbase + u];
            Bt[rr * STR1 + cbase + u] = Bbuf[(long)(j0 + rr) * 256 + cbase + u];
        }
        b1s[tid] = b1[tid];
    }
    __syncthreads();
    int w = tid >> 6;
    int lane = tid & 63;          // pair id
    int ii = lane >> 3, jj = lane & 7;
    // phase 2: h1 (on the fly) -> h2
    #pragma unroll 1
    for (int blk = 0; blk < 4; blk++) {
        int c2b = __builtin_amdgcn_readfirstlane(w * 32 + blk * 8);
        float acc[8] = {};
        #pragma unroll 4
        for (int c1 = 0; c1 < 256; c1++) {
            float h1v = At[ii * STR1 + c1] + Bt[jj * STR1 + c1] + b1s[c1];
            h1v = fmaxf(h1v, 0.f);
            const float* wrow = W2T + c1 * 128 + c2b;
            #pragma unroll
            for (int u = 0; u < 8; u++) acc[u] += wrow[u] * h1v;
        }
        #pragma unroll
        for (int u = 0; u < 8; u++)
            h2s[lane * STR2 + c2b + u] = fmaxf(acc[u] + b2[c2b + u], 0.f);
    }
    __syncthreads();
    // phase 3: h2 -> h3, W4 fused
    float sp = 0.f;
    #pragma unroll 1
    for (int blk = 0; blk < 2; blk++) {
        int c3b = __builtin_amdgcn_readfirstlane(w * 16 + blk * 8);
        float acc[8] = {};
        #pragma unroll 4
        for (int c2 = 0; c2 < 128; c2++) {
            float h2v = h2s[lane * STR2 + c2];
            const float* wrow = W3T + c2 * 64 + c3b;
            #pragma unroll
            for (int u = 0; u < 8; u++) acc[u] += wrow[u] * h2v;
        }
        #pragma unroll
        for (int u = 0; u < 8; u++) {
            float v = fmaxf(acc[u] + b3[c3b + u], 0.f);
            sp += W4[c3b + u] * v;
        }
    }
    spart[w * 64 + lane] = sp;
    __syncthreads();
    if (tid < 64) {
        float s = spart[tid] + spart[64 + tid] + spart[128 + tid] + spart[192 + tid] + b4[0];
        int i = i0 + (tid >> 3), j = j0 + (tid & 7);
        if (i < NN && j < NN) S[(long)i * NN + j] = s;
    }
}

// ---------------------------------------------------------------- softmax+loss
__global__ __launch_bounds__(256)
void softmax_row(const float* __restrict__ S, const int* __restrict__ heads,
                 float* __restrict__ probs, float* __restrict__ rowloss)
{
    int i = blockIdx.x;
    int tid = threadIdx.x;
    __shared__ float red[256];
    __shared__ float srow[NN];
    const float* Si = S + (long)i * NN;
    float mx = -1e30f;
    for (int j = tid; j < NN; j += 256) { float v = Si[j]; srow[j] = v; mx = fmaxf(mx, v); }
    red[tid] = mx; __syncthreads();
    for (int s = 128; s > 0; s >>= 1) { if (tid < s) red[tid] = fmaxf(red[tid], red[tid + s]); __syncthreads(); }
    mx = red[0]; __syncthreads();
    float sum = 0.f, sq = 0.f;
    int hd = heads[i];
    for (int j = tid; j < NN; j += 256) {
        float v = srow[j];
        sum += __expf(v - mx);
        float t = (j == hd) ? 100.f : 0.f;
        float d = v - t; sq += d * d;
    }
    red[tid] = sum; __syncthreads();
    for (int s = 128; s > 0; s >>= 1) { if (tid < s) red[tid] += red[tid + s]; __syncthreads(); }
    sum = red[0]; __syncthreads();
    red[tid] = sq; __syncthreads();
    for (int s = 128; s > 0; s >>= 1) { if (tid < s) red[tid] += red[tid + s]; __syncthreads(); }
    if (tid == 0) rowloss[i] = red[0];
    float inv = 1.f / sum;
    for (int j = tid; j < NN; j += 256) probs[(long)i * NN + j] = __expf(srow[j] - mx) * inv;
}

__global__ __launch_bounds__(256)
void finish_loss(const float* __restrict__ rowloss, float* __restrict__ out0)
{
    __shared__ float red[256];
    int tid = threadIdx.x;
    float s = 0.f;
    for (int i = tid; i < NN; i += 256) s += rowloss[i];
    red[tid] = s; __syncthreads();
    for (int k = 128; k > 0; k >>= 1) { if (tid < k) red[tid] += red[tid + k]; __syncthreads(); }
    if (tid == 0) out0[0] = red[0] / ((float)NN * (float)NN);
}

// ---------------------------------------------------------------- launch
extern "C" void kernel_launch(void* const* d_in, const int* in_sizes, int n_in,
                              void* d_out, int out_size, void* d_ws, size_t ws_size,
                              hipStream_t stream)
{
    const float* x     = (const float*)d_in[0];
    const int*   heads = (const int*)  d_in[1];
    const float* Wih0  = (const float*)d_in[2];
    const float* Whh0  = (const float*)d_in[3];
    const float* b0    = (const float*)d_in[4];
    const float* Wih_r = (const float*)d_in[5];
    const float* Whh_r = (const float*)d_in[6];
    const float* b_r   = (const float*)d_in[7];
    const float* W1    = (const float*)d_in[8];
    const float* b1    = (const float*)d_in[9];
    const float* W2    = (const float*)d_in[10];
    const float* b2    = (const float*)d_in[11];
    const float* W3    = (const float*)d_in[12];
    const float* b3    = (const float*)d_in[13];
    const float* W4    = (const float*)d_in[14];
    const float* b4    = (const float*)d_in[15];
    float* out = (float*)d_out;

    char* ws = (char*)d_ws;
    // ws layout (bytes)
    const size_t o_zin  = 0;                       // 2*512*2048 f = 8 MB
    const size_t o_outA = o_zin  + (size_t)2 * SEQ * H4 * 4 + 512;
    const size_t o_outB = o_outA + (size_t)SEQ * H2 * 4 + 512;
    const size_t o_avail= o_outB + (size_t)SEQ * H2 * 4 + 512;
    const size_t o_Abuf = o_avail+ (size_t)MPAD * H2 * 4 + 512;
    const size_t o_Bbuf = o_Abuf + (size_t)MPAD * 256 * 4 + 512;
    const size_t o_W2T  = o_Bbuf + (size_t)MPAD * 256 * 4 + 512;
    const size_t o_W3T  = o_W2T  + 256 * 128 * 4 + 512;
    const size_t o_S    = o_W3T  + 128 * 64 * 4 + 512;
    const size_t o_rl   = o_S    + (size_t)NN * NN * 4 + 512;

    float* zin   = (float*)(ws + o_zin);
    float* outA  = (float*)(ws + o_outA);
    float* outB  = (float*)(ws + o_outB);
    float* avail = (float*)(ws + o_avail);
    float* Abuf  = (float*)(ws + o_Abuf);
    float* Bbuf  = (float*)(ws + o_Bbuf);
    float* W2T   = (float*)(ws + o_W2T);
    float* W3T   = (float*)(ws + o_W3T);
    float* Sbuf  = (float*)(ws + o_S);
    float* rowl  = (float*)(ws + o_rl);

    const size_t outBytes = (size_t)SEQ * H2 * 4;   // 2 MB

    // layer 0
    gemm_nt<<<dim3(H4 / 64, SEQ / 64, 2), 256, 0, stream>>>(
        x, EMB, 0, Wih0, EMB, (long)H4 * EMB, b0, H4,
        zin, H4, (long)SEQ * H4, EMB);
    hipMemsetAsync(outA, 0xFF, outBytes, stream);   // sentinel fill for poll
    lstm_layer<<<256, 256, 0, stream>>>(zin, Whh0, outA);

    // layers 1..3 (dst pre-filled 0xFF after its last reader finished)
    float* bufs[2] = { outA, outB };
    for (int l = 1; l <= 3; l++) {
        const float* src = bufs[(l - 1) & 1];
        float* dst = bufs[l & 1];
        gemm_nt<<<dim3(H4 / 64, SEQ / 64, 2), 256, 0, stream>>>(
            src, H2, 0, Wih_r + (size_t)(l - 1) * 2 * H4 * H2, H2, (long)H4 * H2,
            b_r + (size_t)(l - 1) * 2 * H4, H4,
            zin, H4, (long)SEQ * H4, H2);
        hipMemsetAsync(dst, 0xFF, outBytes, stream);
        lstm_layer<<<256, 256, 0, stream>>>(
            zin, Whh_r + (size_t)(l - 1) * 2 * H4 * HID, dst);
    }
    float* lstm_final = bufs[3 & 1];   // outB

    build_avail<<<(MPAD * H2) / 256, 256, 0, stream>>>(lstm_final, avail);

    // A = avail @ W1[:, :1024].T ; B = avail @ W1[:, 1024:].T
    gemm_nt<<<dim3(256 / 64, MPAD / 64, 1), 256, 0, stream>>>(
        avail, H2, 0, W1, 2048, 0, nullptr, 0, Abuf, 256, 0, H2);
    gemm_nt<<<dim3(256 / 64, MPAD / 64, 1), 256, 0, stream>>>(
        avail, H2, 0, W1 + 1024, 2048, 0, nullptr, 0, Bbuf, 256, 0, H2);

    transpose_w<<<(128 * 256) / 256, 256, 0, stream>>>(W2, W2T, 128, 256);
    transpose_w<<<(64 * 128) / 256, 256, 0, stream>>>(W3, W3T, 64, 128);

    pair_kernel<<<dim3(65, 65), 256, 0, stream>>>(
        Abuf, Bbuf, b1, W2T, b2, W3T, b3, W4, b4, Sbuf);

    softmax_row<<<NN, 256, 0, stream>>>(Sbuf, heads, out + 1, rowl);
    finish_loss<<<1, 256, 0, stream>>>(rowl, out);
}

// Round 8
// 6491.923 us; speedup vs baseline: 1.2978x; 1.2978x over previous
//
#include <hip/hip_runtime.h>
#include <math.h>

#define HID 512
#define SEQ 512
#define EMB 345
#define NN  513
#define MPAD 576
#define H4  2048
#define H2  1024

// ---------------------------------------------------------------- GEMM (NT)
// C[m][n] = sum_k A[m][k]*B[n][k] (+ bias[n]); BM=BN=64, TK=16, 256 thr, 4x4
__global__ __launch_bounds__(256)
void gemm_nt(const float* __restrict__ A, int lda, long aStride,
             const float* __restrict__ B, int ldb, long bStride,
             const float* __restrict__ bias, long biasStride,
             float* __restrict__ C, int ldc, long cStride, int K)
{
    int z = blockIdx.z;
    A += (long)z * aStride; B += (long)z * bStride; C += (long)z * cStride;
    const float* bptr = bias ? bias + (long)z * biasStride : nullptr;
    __shared__ float As[16][68];
    __shared__ float Bs[16][68];
    int tid = threadIdx.x;
    int tx = tid & 15, ty = tid >> 4;
    int m0 = blockIdx.y * 64, n0 = blockIdx.x * 64;
    float acc[4][4] = {};
    for (int k0 = 0; k0 < K; k0 += 16) {
        #pragma unroll
        for (int i = 0; i < 4; i++) {
            int id = tid + 256 * i;
            int mn = id >> 4, kk = id & 15;
            int k = k0 + kk;
            As[kk][mn] = (k < K) ? A[(long)(m0 + mn) * lda + k] : 0.f;
            Bs[kk][mn] = (k < K) ? B[(long)(n0 + mn) * ldb + k] : 0.f;
        }
        __syncthreads();
        #pragma unroll
        for (int kk = 0; kk < 16; kk++) {
            float a[4], b[4];
            #pragma unroll
            for (int i = 0; i < 4; i++) a[i] = As[kk][ty * 4 + i];
            #pragma unroll
            for (int j = 0; j < 4; j++) b[j] = Bs[kk][tx * 4 + j];
            #pragma unroll
            for (int i = 0; i < 4; i++)
                #pragma unroll
                for (int j = 0; j < 4; j++) acc[i][j] += a[i] * b[j];
        }
        __syncthreads();
    }
    #pragma unroll
    for (int i = 0; i < 4; i++) {
        int m = m0 + ty * 4 + i;
        #pragma unroll
        for (int j = 0; j < 4; j++) {
            int n = n0 + tx * 4 + j;
            float v = acc[i][j];
            if (bptr) v += bptr[n];
            C[(long)m * ldc + n] = v;
        }
    }
}

// ---------------------------------------------------------------- LSTM layer
// fast activations: v_exp_f32 + v_rcp_f32 (~1e-6 rel err; tolerance is 0.39)
__device__ __forceinline__ float sigmf(float x)
{ return __builtin_amdgcn_rcpf(1.f + __expf(-x)); }
__device__ __forceinline__ float tanhf_fast(float x)
{ return 1.f - 2.f * __builtin_amdgcn_rcpf(1.f + __expf(2.f * x)); }
// x=+inf: exp=inf, rcp=0 -> 1; x=-inf: exp=0 -> -1. No NaN.

__device__ __forceinline__ bool badw(unsigned long long a)
{ return ((unsigned)a == 0xFFFFFFFFu) || ((unsigned)(a >> 32) == 0xFFFFFFFFu); }

// 128 WGs: wg>>6 = dir, (wg&63)*8 = cell base (8 cells/WG).
// Lane map tid = ci*32 + g*8 + kp (ci cell 0..7, g gate 0..3, kp k-eighth).
// Weights in LDS row-major: w_lds[tid][64] at stride 68 floats (17 float4 ->
// phase-group banks (t+j)%8 distinct = conflict-free b128). The ONLY
// deterministic residency is LDS (R1/R5/R7: allocator refuses VGPR arrays).
// Per step: the 16 weight ds_read_b128 are pre-issued BEFORE the barrier
// and pinned with sched_barrier(0) so they overlap the poll window (R6's
// failure: compiler sank them). Poll = 1 ull/thread, data-as-flag 0xFF
// sentinel; h staged at stride 68 (conflict-free both sides), double-
// buffered, ONE barrier/step. k-reduce 3 shfl_xor; gate gather 3 shfl;
// activation+publish on lanes tid%32==0.
__global__ __launch_bounds__(256, 1)
void lstm_layer(const float* __restrict__ zin,   // [2][SEQ][H4]
                const float* __restrict__ Whh,   // [2][H4][HID]
                float* out)                      // [SEQ][H2], pre-memset 0xFF
{
    int wg  = blockIdx.x;
    int dir = wg >> 6;
    int cb  = (wg & 63) * 8;
    int tid = threadIdx.x;
    int ci  = tid >> 5;          // cell in group 0..7
    int g   = (tid >> 3) & 3;    // gate (torch order i,f,g,o)
    int kp  = tid & 7;           // k-eighth (64 floats)
    int l   = tid & 63;
    int cell = cb + ci;
    long row = (long)g * 512 + cell;

    __shared__ __align__(16) float w_lds[256 * 68];   // [tid][64] + 4 pad, 69.6 KB
    __shared__ __align__(16) float h_st[2][8 * 68];   // dbuf h, 8 chunks of 64 + pad

    // one-time weight staging: thread's 64 weights -> own contiguous row
    {
        const float4* wp = (const float4*)(Whh + ((long)dir * H4 + row) * HID + kp * 64);
        float4* wd = (float4*)w_lds + 17 * tid;
        #pragma unroll
        for (int j = 0; j < 16; j++) wd[j] = wp[j];
    }

    const float* zin_d = zin + (long)dir * SEQ * H4;
    float c_st = 0.f;
    int hc = tid >> 5;           // staging chunk (element e=2*tid, chunk=e>>6)
    int ho = 2 * (tid & 31);     // offset within chunk

    for (int t = 0; t < SEQ; t++) {
        int at = (dir == 0) ? t : (SEQ - 1 - t);
        // zin prefetch (kp==0 lanes only), issued before the poll
        float zv = 0.f;
        if (kp == 0) zv = zin_d[(long)at * H4 + row];

        if (t == 0) {
            *(float2*)&h_st[0][hc * 68 + ho] = make_float2(0.f, 0.f);
        } else {
            int at_prev = (dir == 0) ? (t - 1) : (SEQ - t);
            const unsigned long long* src =
                (const unsigned long long*)(out + (long)at_prev * H2 + dir * HID) + tid;
            unsigned long long a = __hip_atomic_load(src, __ATOMIC_RELAXED, __HIP_MEMORY_SCOPE_AGENT);
            while (badw(a)) {
                __builtin_amdgcn_s_sleep(1);
                a = __hip_atomic_load(src, __ATOMIC_RELAXED, __HIP_MEMORY_SCOPE_AGENT);
            }
            union { unsigned long long u; float2 f; } cv; cv.u = a;
            *(float2*)&h_st[t & 1][hc * 68 + ho] = cv.f;
        }

        // pre-issue weight reads (LDS pipe idle during poll); pin with a
        // scheduling fence so they cannot sink below the barrier
        float4 wv[16];
        {
            const float4* wr = (const float4*)w_lds + 17 * tid;
            #pragma unroll
            for (int j = 0; j < 16; j++) wv[j] = wr[j];
        }
        __builtin_amdgcn_sched_barrier(0);
        __syncthreads();       // the ONLY barrier per step (dbuf protects reuse)

        // MAC over own k-eighth: h chunk kp (stride 17 float4, phase-distinct)
        const float4* hp = (const float4*)&h_st[t & 1][kp * 68];
        float acc = 0.f;
        #pragma unroll
        for (int j = 0; j < 16; j++) {
            float4 h = hp[j];
            acc += wv[j].x * h.x + wv[j].y * h.y + wv[j].z * h.z + wv[j].w * h.w;
        }
        // k-reduce within the 8-lane gate group
        acc += __shfl_xor(acc, 1);
        acc += __shfl_xor(acc, 2);
        acc += __shfl_xor(acc, 4);
        float zsum = acc + zv;             // full gate preact on kp==0 lanes
        // gate gather (intra-wave): act lane l&32 reads lanes +8/+16/+24
        float zf = __shfl(zsum, (l & 32) + 8);
        float zg = __shfl(zsum, (l & 32) + 16);
        float zo = __shfl(zsum, (l & 32) + 24);
        if ((tid & 31) == 0) {
            float cc = sigmf(zf) * c_st + sigmf(zsum) * tanhf_fast(zg);
            c_st = cc;
            float hh = sigmf(zo) * tanhf_fast(cc);
            // single publish: the out-write IS the ready flag
            __hip_atomic_store(out + (long)at * H2 + dir * HID + cell, hh,
                               __ATOMIC_RELAXED, __HIP_MEMORY_SCOPE_AGENT);
        }
    }
}

// ---------------------------------------------------------------- avail build
__global__ __launch_bounds__(256)
void build_avail(const float* __restrict__ lstm_out, float* __restrict__ avail)
{
    long idx = (long)blockIdx.x * 256 + threadIdx.x;   // over MPAD*H2
    if (idx >= (long)MPAD * H2) return;
    int i = (int)(idx >> 10);
    int c = (int)(idx & 1023);
    float v = 0.f;
    if (i >= 1 && i <= SEQ) v = lstm_out[(long)(i - 1) * H2 + c];
    avail[idx] = v;
}

// ---------------------------------------------------------------- transpose
__global__ __launch_bounds__(256)
void transpose_w(const float* __restrict__ W, float* __restrict__ WT, int rows, int cols)
{
    int idx = blockIdx.x * 256 + threadIdx.x;
    if (idx >= rows * cols) return;
    int rr = idx / cols, cc = idx % cols;
    WT[cc * rows + rr] = W[idx];
}

// ---------------------------------------------------------------- pair MLP
#define STR1 257
#define STR2 129
__global__ __launch_bounds__(256)
void pair_kernel(const float* __restrict__ Abuf, const float* __restrict__ Bbuf,
                 const float* __restrict__ b1, const float* __restrict__ W2T,
                 const float* __restrict__ b2, const float* __restrict__ W3T,
                 const float* __restrict__ b3, const float* __restrict__ W4,
                 const float* __restrict__ b4, float* __restrict__ S)
{
    __shared__ float At[8 * STR1];
    __shared__ float Bt[8 * STR1];
    __shared__ float b1s[256];
    __shared__ float h2s[64 * STR2];
    __shared__ float spart[4 * 64];
    int tid = threadIdx.x;
    int i0 = blockIdx.y * 8, j0 = blockIdx.x * 8;
    {
        int rr = tid >> 5;
        int cbase = (tid & 31) * 8;
        #pragma unroll
        for (int u = 0; u < 8; u++) {
            At[rr * STR1 + cbase + u] = Abuf[(long)(i0 + rr) * 256 + cbase + u];
            Bt[rr * STR1 + cbase + u] = Bbuf[(long)(j0 + rr) * 256 + cbase + u];
        }
        b1s[tid] = b1[tid];
    }
    __syncthreads();
    int w = tid >> 6;
    int lane = tid & 63;          // pair id
    int ii = lane >> 3, jj = lane & 7;
    // phase 2: h1 (on the fly) -> h2
    #pragma unroll 1
    for (int blk = 0; blk < 4; blk++) {
        int c2b = __builtin_amdgcn_readfirstlane(w * 32 + blk * 8);
        float acc[8] = {};
        #pragma unroll 4
        for (int c1 = 0; c1 < 256; c1++) {
            float h1v = At[ii * STR1 + c1] + Bt[jj * STR1 + c1] + b1s[c1];
            h1v = fmaxf(h1v, 0.f);
            const float* wrow = W2T + c1 * 128 + c2b;
            #pragma unroll
            for (int u = 0; u < 8; u++) acc[u] += wrow[u] * h1v;
        }
        #pragma unroll
        for (int u = 0; u < 8; u++)
            h2s[lane * STR2 + c2b + u] = fmaxf(acc[u] + b2[c2b + u], 0.f);
    }
    __syncthreads();
    // phase 3: h2 -> h3, W4 fused
    float sp = 0.f;
    #pragma unroll 1
    for (int blk = 0; blk < 2; blk++) {
        int c3b = __builtin_amdgcn_readfirstlane(w * 16 + blk * 8);
        float acc[8] = {};
        #pragma unroll 4
        for (int c2 = 0; c2 < 128; c2++) {
            float h2v = h2s[lane * STR2 + c2];
            const float* wrow = W3T + c2 * 64 + c3b;
            #pragma unroll
            for (int u = 0; u < 8; u++) acc[u] += wrow[u] * h2v;
        }
        #pragma unroll
        for (int u = 0; u < 8; u++) {
            float v = fmaxf(acc[u] + b3[c3b + u], 0.f);
            sp += W4[c3b + u] * v;
        }
    }
    spart[w * 64 + lane] = sp;
    __syncthreads();
    if (tid < 64) {
        float s = spart[tid] + spart[64 + tid] + spart[128 + tid] + spart[192 + tid] + b4[0];
        int i = i0 + (tid >> 3), j = j0 + (tid & 7);
        if (i < NN && j < NN) S[(long)i * NN + j] = s;
    }
}

// ---------------------------------------------------------------- softmax+loss
__global__ __launch_bounds__(256)
void softmax_row(const float* __restrict__ S, const int* __restrict__ heads,
                 float* __restrict__ probs, float* __restrict__ rowloss)
{
    int i = blockIdx.x;
    int tid = threadIdx.x;
    __shared__ float red[256];
    __shared__ float srow[NN];
    const float* Si = S + (long)i * NN;
    float mx = -1e30f;
    for (int j = tid; j < NN; j += 256) { float v = Si[j]; srow[j] = v; mx = fmaxf(mx, v); }
    red[tid] = mx; __syncthreads();
    for (int s = 128; s > 0; s >>= 1) { if (tid < s) red[tid] = fmaxf(red[tid], red[tid + s]); __syncthreads(); }
    mx = red[0]; __syncthreads();
    float sum = 0.f, sq = 0.f;
    int hd = heads[i];
    for (int j = tid; j < NN; j += 256) {
        float v = srow[j];
        sum += __expf(v - mx);
        float t = (j == hd) ? 100.f : 0.f;
        float d = v - t; sq += d * d;
    }
    red[tid] = sum; __syncthreads();
    for (int s = 128; s > 0; s >>= 1) { if (tid < s) red[tid] += red[tid + s]; __syncthreads(); }
    sum = red[0]; __syncthreads();
    red[tid] = sq; __syncthreads();
    for (int s = 128; s > 0; s >>= 1) { if (tid < s) red[tid] += red[tid + s]; __syncthreads(); }
    if (tid == 0) rowloss[i] = red[0];
    float inv = 1.f / sum;
    for (int j = tid; j < NN; j += 256) probs[(long)i * NN + j] = __expf(srow[j] - mx) * inv;
}

__global__ __launch_bounds__(256)
void finish_loss(const float* __restrict__ rowloss, float* __restrict__ out0)
{
    __shared__ float red[256];
    int tid = threadIdx.x;
    float s = 0.f;
    for (int i = tid; i < NN; i += 256) s += rowloss[i];
    red[tid] = s; __syncthreads();
    for (int k = 128; k > 0; k >>= 1) { if (tid < k) red[tid] += red[tid + k]; __syncthreads(); }
    if (tid == 0) out0[0] = red[0] / ((float)NN * (float)NN);
}

// ---------------------------------------------------------------- launch
extern "C" void kernel_launch(void* const* d_in, const int* in_sizes, int n_in,
                              void* d_out, int out_size, void* d_ws, size_t ws_size,
                              hipStream_t stream)
{
    const float* x     = (const float*)d_in[0];
    const int*   heads = (const int*)  d_in[1];
    const float* Wih0  = (const float*)d_in[2];
    const float* Whh0  = (const float*)d_in[3];
    const float* b0    = (const float*)d_in[4];
    const float* Wih_r = (const float*)d_in[5];
    const float* Whh_r = (const float*)d_in[6];
    const float* b_r   = (const float*)d_in[7];
    const float* W1    = (const float*)d_in[8];
    const float* b1    = (const float*)d_in[9];
    const float* W2    = (const float*)d_in[10];
    const float* b2    = (const float*)d_in[11];
    const float* W3    = (const float*)d_in[12];
    const float* b3    = (const float*)d_in[13];
    const float* W4    = (const float*)d_in[14];
    const float* b4    = (const float*)d_in[15];
    float* out = (float*)d_out;

    char* ws = (char*)d_ws;
    // ws layout (bytes)
    const size_t o_zin  = 0;                       // 2*512*2048 f = 8 MB
    const size_t o_outA = o_zin  + (size_t)2 * SEQ * H4 * 4 + 512;
    const size_t o_outB = o_outA + (size_t)SEQ * H2 * 4 + 512;
    const size_t o_avail= o_outB + (size_t)SEQ * H2 * 4 + 512;
    const size_t o_Abuf = o_avail+ (size_t)MPAD * H2 * 4 + 512;
    const size_t o_Bbuf = o_Abuf + (size_t)MPAD * 256 * 4 + 512;
    const size_t o_W2T  = o_Bbuf + (size_t)MPAD * 256 * 4 + 512;
    const size_t o_W3T  = o_W2T  + 256 * 128 * 4 + 512;
    const size_t o_S    = o_W3T  + 128 * 64 * 4 + 512;
    const size_t o_rl   = o_S    + (size_t)NN * NN * 4 + 512;

    float* zin   = (float*)(ws + o_zin);
    float* outA  = (float*)(ws + o_outA);
    float* outB  = (float*)(ws + o_outB);
    float* avail = (float*)(ws + o_avail);
    float* Abuf  = (float*)(ws + o_Abuf);
    float* Bbuf  = (float*)(ws + o_Bbuf);
    float* W2T   = (float*)(ws + o_W2T);
    float* W3T   = (float*)(ws + o_W3T);
    float* Sbuf  = (float*)(ws + o_S);
    float* rowl  = (float*)(ws + o_rl);

    const size_t outBytes = (size_t)SEQ * H2 * 4;   // 2 MB

    // layer 0
    gemm_nt<<<dim3(H4 / 64, SEQ / 64, 2), 256, 0, stream>>>(
        x, EMB, 0, Wih0, EMB, (long)H4 * EMB, b0, H4,
        zin, H4, (long)SEQ * H4, EMB);
    hipMemsetAsync(outA, 0xFF, outBytes, stream);   // sentinel fill for poll
    lstm_layer<<<128, 256, 0, stream>>>(zin, Whh0, outA);

    // layers 1..3 (dst pre-filled 0xFF after its last reader finished)
    float* bufs[2] = { outA, outB };
    for (int l = 1; l <= 3; l++) {
        const float* src = bufs[(l - 1) & 1];
        float* dst = bufs[l & 1];
        gemm_nt<<<dim3(H4 / 64, SEQ / 64, 2), 256, 0, stream>>>(
            src, H2, 0, Wih_r + (size_t)(l - 1) * 2 * H4 * H2, H2, (long)H4 * H2,
            b_r + (size_t)(l - 1) * 2 * H4, H4,
            zin, H4, (long)SEQ * H4, H2);
        hipMemsetAsync(dst, 0xFF, outBytes, stream);
        lstm_layer<<<128, 256, 0, stream>>>(
            zin, Whh_r + (size_t)(l - 1) * 2 * H4 * HID, dst);
    }
    float* lstm_final = bufs[3 & 1];   // outB

    build_avail<<<(MPAD * H2) / 256, 256, 0, stream>>>(lstm_final, avail);

    // A = avail @ W1[:, :1024].T ; B = avail @ W1[:, 1024:].T
    gemm_nt<<<dim3(256 / 64, MPAD / 64, 1), 256, 0, stream>>>(
        avail, H2, 0, W1, 2048, 0, nullptr, 0, Abuf, 256, 0, H2);
    gemm_nt<<<dim3(256 / 64, MPAD / 64, 1), 256, 0, stream>>>(
        avail, H2, 0, W1 + 1024, 2048, 0, nullptr, 0, Bbuf, 256, 0, H2);

    transpose_w<<<(128 * 256) / 256, 256, 0, stream>>>(W2, W2T, 128, 256);
    transpose_w<<<(64 * 128) / 256, 256, 0, stream>>>(W3, W3T, 64, 128);

    pair_kernel<<<dim3(65, 65), 256, 0, stream>>>(
        Abuf, Bbuf, b1, W2T, b2, W3T, b3, W4, b4, Sbuf);

    softmax_row<<<NN, 256, 0, stream>>>(Sbuf, heads, out + 1, rowl);
    finish_loss<<<1, 256, 0, stream>>>(rowl, out);
}